// Round 3
// baseline (1064.052 us; speedup 1.0000x reference)
//
#include <hip/hip_runtime.h>

typedef __bf16 bf16x8 __attribute__((ext_vector_type(8)));
typedef float  f32x16 __attribute__((ext_vector_type(16)));

#define GAS(p) ((const __attribute__((address_space(1))) void*)(p))
#define LAS(p) ((__attribute__((address_space(3))) void*)(p))

__device__ __forceinline__ float gelu_exact(float x) {
    return 0.5f * x * (1.f + erff(x * 0.70710678118654752440f));
}

// ---------------------------------------------------------------------------
// Stage 1: per-point features. One wave per point, 4 points per 256-thr block.
// G row (192 bf16): [0:40)=fourier, [40:148)=gelu patch-MLP hidden, [148:192)=0.
// ---------------------------------------------------------------------------
__global__ __launch_bounds__(256) void stage1_kernel(
    const float* __restrict__ query, const float* __restrict__ images,
    const float* __restrict__ pm_w1, const float* __restrict__ pm_b1,
    __bf16* __restrict__ G, int* __restrict__ tbuf)
{
    __shared__ float patch[4][28];
    const int wave = threadIdx.x >> 6, lane = threadIdx.x & 63;
    const int p = blockIdx.x * 4 + wave;
    const float* q = query + (size_t)p * 5;
    float u = fminf(fmaxf(q[0], 0.f), 1.f);
    float v = fminf(fmaxf(q[1], 0.f), 1.f);
    int ts = min(max((int)rintf(q[2]), 0), 47);
    int tt = min(max((int)rintf(q[3]), 0), 47);
    int tc = min(max((int)rintf(q[4]), 0), 47);
    const int b = p >> 13;  // N = 8192 points per batch
    if (lane < 27) {
        int c = lane / 9, rem = lane % 9, dy = rem / 3, dx = rem % 3;
        int x = (int)rintf(u * 255.f), y = (int)rintf(v * 255.f);
        int xx = min(max(x + dx - 1, 0), 255);
        int yy = min(max(y + dy - 1, 0), 255);
        size_t idx = ((size_t)((b * 3 + c) * 48 + ts) << 16) + ((size_t)yy << 8) + (size_t)xx;
        patch[wave][lane] = images[idx];
    }
    if (lane < 40) {
        int i = lane % 10;
        float base = (lane < 20) ? u : v;
        float ph = 6.28318530717958647693f * base * exp2f((float)i);
        float val = ((lane / 10) & 1) ? cosf(ph) : sinf(ph);
        G[(size_t)p * 192 + lane] = (__bf16)val;
    }
    for (int j = 148 + lane; j < 192; j += 64) G[(size_t)p * 192 + j] = (__bf16)0.f;
    if (lane < 3) tbuf[p * 3 + lane] = (lane == 0) ? ts : (lane == 1) ? tt : tc;
    __syncthreads();
    for (int j = lane; j < 108; j += 64) {
        float acc = pm_b1[j];
        #pragma unroll
        for (int i2 = 0; i2 < 27; i2++)
            acc = fmaf(patch[wave][i2], pm_w1[i2 * 108 + j], acc);
        G[(size_t)p * 192 + 40 + j] = (__bf16)gelu_exact(acc);
    }
}

// ---------------------------------------------------------------------------
// Prepack: transpose f32 (R x C) -> bf16 (C x R)
// ---------------------------------------------------------------------------
__global__ __launch_bounds__(256) void transpose_to_bf16(
    const float* __restrict__ src, __bf16* __restrict__ dst, int R, int C)
{
    __shared__ float t[32][33];
    const int c0 = blockIdx.x * 32, r0 = blockIdx.y * 32;
    const int tx = threadIdx.x & 31, ty = threadIdx.x >> 5;
    #pragma unroll
    for (int i = 0; i < 32; i += 8)
        t[ty + i][tx] = src[(size_t)(r0 + ty + i) * C + (c0 + tx)];
    __syncthreads();
    #pragma unroll
    for (int i = 0; i < 32; i += 8)
        dst[(size_t)(c0 + ty + i) * R + (r0 + tx)] = (__bf16)t[tx][ty + i];
}

// Wcat_t (768 x 192) bf16: row n, k<40 -> uv_w[k][n]; k<148 -> pm_w2[k-40][n]; else 0
__global__ __launch_bounds__(256) void build_wcat(
    const float* __restrict__ uv_w, const float* __restrict__ pm_w2, __bf16* __restrict__ Wt)
{
    int idx = blockIdx.x * 256 + threadIdx.x;  // < 768*192
    int n = idx / 192, k = idx % 192;
    float v = 0.f;
    if (k < 40) v = uv_w[k * 768 + n];
    else if (k < 148) v = pm_w2[(k - 40) * 768 + n];
    Wt[idx] = (__bf16)v;
}

// ---------------------------------------------------------------------------
// bf16 MFMA GEMM, big-wave-tile: C(MxN) = A(MxK) @ Bt(NxK)^T.
// Block tile 256x128, 4 waves (2x2) of 128x64 each, mfma_f32_32x32x16_bf16
// (4x2 tiles/wave, 128 acc VGPRs). BK=64 -> LDS 48 KB -> 3 blocks/CU.
// LDS stored subtile-major (32 rows x 16 k = 1 KB slots) so both
// global_load_lds and ds_read_b128 are exactly base + lane*16: conflict-free,
// zero layout shuffling. Requires K%64==0, M%2048==0, N%128==0.
// XCD swizzle: blocks sharing an A-panel sit 8 ids apart (same XCD L2).
// ---------------------------------------------------------------------------
enum { EPI_X = 0, EPI_GELU = 1, EPI_OUT = 2 };

template <int EPI, typename OutT>
__global__ __launch_bounds__(256, 3) void gemm_bt(
    const __bf16* __restrict__ A, const __bf16* __restrict__ Bt, int K,
    const float* __restrict__ bias, const float* __restrict__ bias2,
    const int* __restrict__ tbuf,
    const float* __restrict__ e0, const float* __restrict__ e1, const float* __restrict__ e2,
    OutT* __restrict__ Cmat, int N)
{
    __shared__ __attribute__((aligned(16))) __bf16 As[256 * 64];  // 32 KB, 32 slots
    __shared__ __attribute__((aligned(16))) __bf16 Bs[128 * 64];  // 16 KB, 16 slots
    const int tid = threadIdx.x;
    const int w = tid >> 6, lane = tid & 63;
    const int wr = w >> 1, wc = w & 1;
    const int l31 = lane & 31, half = lane >> 5;

    const int ntiles = N >> 7;
    const int per_super = ntiles << 3;
    const int id = blockIdx.x;
    const int sup = id / per_super, rem = id - sup * per_super;
    const long m0 = (long)(sup * 8 + (rem & 7)) << 8;   // 256-row m-tile
    const long n0 = (long)(rem >> 3) << 7;              // 128-col n-tile

    f32x16 acc[4][2];
    #pragma unroll
    for (int i = 0; i < 4; i++)
        #pragma unroll
        for (int j = 0; j < 2; j++)
            #pragma unroll
            for (int r = 0; r < 16; r++)
                acc[i][j][r] = 0.f;

    // Per-lane global bases: lane lambda covers (row = +l31, k = +half*8).
    const __bf16* a_lane = A  + (m0 + l31) * (long)K + half * 8;
    const __bf16* b_lane = Bt + (n0 + l31) * (long)K + half * 8;

    for (int kt = 0; kt < K; kt += 64) {
        // A: wave w stages slots w*8..w*8+7 (slot = mi*4+ks, mi=row/32, ks=k/16)
        #pragma unroll
        for (int s = 0; s < 8; s++) {
            const int slot = w * 8 + s;
            const int mi = slot >> 2, ks = slot & 3;
            __builtin_amdgcn_global_load_lds(
                GAS(a_lane + (long)mi * 32 * K + kt + ks * 16),
                LAS(As + slot * 512), 16, 0, 0);
        }
        // B: wave w stages nj = w (cols w*32..w*32+31), slots w*4+ks
        #pragma unroll
        for (int ks = 0; ks < 4; ks++) {
            __builtin_amdgcn_global_load_lds(
                GAS(b_lane + (long)w * 32 * K + kt + ks * 16),
                LAS(Bs + (w * 4 + ks) * 512), 16, 0, 0);
        }
        __syncthreads();
        #pragma unroll
        for (int ks = 0; ks < 4; ks++) {
            bf16x8 af[4];
            #pragma unroll
            for (int mi2 = 0; mi2 < 4; mi2++)
                af[mi2] = *(const bf16x8*)&As[((wr * 4 + mi2) * 4 + ks) * 512 + lane * 8];
            #pragma unroll
            for (int nj2 = 0; nj2 < 2; nj2++) {
                bf16x8 bfr = *(const bf16x8*)&Bs[((wc * 2 + nj2) * 4 + ks) * 512 + lane * 8];
                #pragma unroll
                for (int mi2 = 0; mi2 < 4; mi2++)
                    acc[mi2][nj2] = __builtin_amdgcn_mfma_f32_32x32x16_bf16(
                        af[mi2], bfr, acc[mi2][nj2], 0, 0, 0);
            }
        }
        __syncthreads();
    }

    // C/D layout (32x32, m74/m101): col = lane&31, row = (reg&3)+8*(reg>>2)+4*half
    #pragma unroll
    for (int mi2 = 0; mi2 < 4; mi2++) {
        #pragma unroll
        for (int r = 0; r < 16; r++) {
            const long row = m0 + (wr * 4 + mi2) * 32 + (r & 3) + ((r >> 2) & 3) * 8 + half * 4;
            int t0 = 0, t1 = 0, t2 = 0;
            if constexpr (EPI == EPI_X) {
                t0 = tbuf[row * 3 + 0];
                t1 = tbuf[row * 3 + 1];
                t2 = tbuf[row * 3 + 2];
            }
            #pragma unroll
            for (int nj2 = 0; nj2 < 2; nj2++) {
                const long col = n0 + (wc * 2 + nj2) * 32 + l31;
                float val = acc[mi2][nj2][r];
                if constexpr (EPI == EPI_X) {
                    val += bias[col] + bias2[col];
                    val += e0[t0 * 768 + col] + e1[t1 * 768 + col] + e2[t2 * 768 + col];
                    Cmat[row * (long)N + col] = (OutT)val;
                } else if constexpr (EPI == EPI_GELU) {
                    val += bias[col];
                    Cmat[row * (long)N + col] = (OutT)gelu_exact(val);
                } else {
                    val += bias[col];
                    Cmat[row * (long)N + col] = (OutT)val;
                }
            }
        }
    }
}

// ---------------------------------------------------------------------------
// workspace layout (bytes, all 256-aligned)
// ---------------------------------------------------------------------------
static constexpr size_t OFF_G  = 0;          // 32768*192*2  = 12582912
static constexpr size_t OFF_T  = 12582912;   // 32768*3*4    = 393216
static constexpr size_t OFF_WC = 12976128;   // 768*192*2    = 294912
static constexpr size_t OFF_W1 = 13271040;   // 3072*768*2   = 4718592
static constexpr size_t OFF_W2 = 17989632;   // 768*3072*2   = 4718592
static constexpr size_t OFF_X  = 22708224;   // 32768*768*2  = 50331648
static constexpr size_t OFF_H2 = 73039872;   // Mc*3072*2

extern "C" void kernel_launch(void* const* d_in, const int* in_sizes, int n_in,
                              void* d_out, int out_size, void* d_ws, size_t ws_size,
                              hipStream_t stream)
{
    const float* query  = (const float*)d_in[0];
    const float* images = (const float*)d_in[1];
    const float* uv_w   = (const float*)d_in[2];
    const float* uv_b   = (const float*)d_in[3];
    const float* e_src  = (const float*)d_in[4];
    const float* e_tgt  = (const float*)d_in[5];
    const float* e_cam  = (const float*)d_in[6];
    const float* pm_w1  = (const float*)d_in[7];
    const float* pm_b1  = (const float*)d_in[8];
    const float* pm_w2  = (const float*)d_in[9];
    const float* pm_b2  = (const float*)d_in[10];
    const float* om_w1  = (const float*)d_in[11];
    const float* om_b1  = (const float*)d_in[12];
    const float* om_w2  = (const float*)d_in[13];
    const float* om_b2  = (const float*)d_in[14];
    float* out = (float*)d_out;
    char* ws = (char*)d_ws;

    __bf16* G    = (__bf16*)(ws + OFF_G);
    int*    tb   = (int*)(ws + OFF_T);
    __bf16* Wcat = (__bf16*)(ws + OFF_WC);
    __bf16* W1t  = (__bf16*)(ws + OFF_W1);
    __bf16* W2t  = (__bf16*)(ws + OFF_W2);
    __bf16* X    = (__bf16*)(ws + OFF_X);
    __bf16* H2   = (__bf16*)(ws + OFF_H2);

    stage1_kernel<<<8192, 256, 0, stream>>>(query, images, pm_w1, pm_b1, G, tb);
    transpose_to_bf16<<<dim3(3072 / 32, 768 / 32), 256, 0, stream>>>(om_w1, W1t, 768, 3072);
    transpose_to_bf16<<<dim3(768 / 32, 3072 / 32), 256, 0, stream>>>(om_w2, W2t, 3072, 768);
    build_wcat<<<576, 256, 0, stream>>>(uv_w, pm_w2, Wcat);

    // X = G @ Wcat^T + uv_b + pm_b2 + embeds   (M=32768, N=768, K=192)
    gemm_bt<EPI_X, __bf16><<<128 * 6, 256, 0, stream>>>(
        G, Wcat, 192, uv_b, pm_b2, tb, e_src, e_tgt, e_cam, X, 768);

    // largest hidden-chunk (multiple of 2048 rows for the 8-m-tile swizzle)
    long Mc = 2048;
    for (long cand = 32768; cand >= 2048; cand >>= 1)
        if (OFF_H2 + (size_t)cand * 3072 * 2 <= ws_size) { Mc = cand; break; }

    for (long m = 0; m < 32768; m += Mc) {
        gemm_bt<EPI_GELU, __bf16><<<(Mc / 256) * 24, 256, 0, stream>>>(
            X + m * 768, W1t, 768, om_b1, nullptr, nullptr, nullptr, nullptr, nullptr, H2, 3072);
        gemm_bt<EPI_OUT, float><<<(Mc / 256) * 6, 256, 0, stream>>>(
            H2, W2t, 3072, om_b2, nullptr, nullptr, nullptr, nullptr, nullptr, out + m * 768, 768);
    }
}